// Round 1
// baseline (785.045 us; speedup 1.0000x reference)
//
#include <hip/hip_runtime.h>
#include <hip/hip_bf16.h>
#include <stdint.h>

#define T_TOK 4096
#define D_DIM 1024
#define F_DIM 4096
#define E_NUM 8
#define NROUTED (T_TOK * 2)

typedef __attribute__((ext_vector_type(8))) __bf16 bf16x8;
typedef __attribute__((ext_vector_type(4))) float f32x4;

// ---- workspace layout (bytes) ----
#define WS_COUNTS 0
#define WS_CURSORS 64
#define WS_OFFSETS 128
#define WS_TOPKI 4096
#define WS_TOPKW (WS_TOPKI + NROUTED * 4)
#define WS_ROWS (WS_TOPKW + NROUTED * 4)
#define WS_DEST (WS_ROWS + NROUTED * 4)
#define WS_XB ((size_t)1 << 20)
#define WS_W1T (WS_XB + (size_t)T_TOK * D_DIM * 2)
#define WS_W2T (WS_W1T + (size_t)E_NUM * D_DIM * F_DIM * 2)
#define WS_H (WS_W2T + (size_t)E_NUM * D_DIM * F_DIM * 2)
#define WS_Y (WS_H + (size_t)NROUTED * F_DIM * 2)

__device__ __forceinline__ unsigned short f2bf(float f) {
  uint32_t u = __float_as_uint(f);
  uint32_t r = (u + 0x7FFFu + ((u >> 16) & 1u)) >> 16;  // RNE
  return (unsigned short)r;
}

__device__ __forceinline__ void gll16(const void* g, void* l) {
  __builtin_amdgcn_global_load_lds(
      (__attribute__((address_space(1))) void*)(void*)(g),
      (__attribute__((address_space(3))) void*)(l), 16, 0, 0);
}

// ---- cast x fp32 -> bf16 ----
__global__ void cast_x_kernel(const float* __restrict__ x, unsigned short* __restrict__ xb) {
  int n4 = T_TOK * D_DIM / 4;
  for (int i = blockIdx.x * blockDim.x + threadIdx.x; i < n4; i += gridDim.x * blockDim.x) {
    float4 v = reinterpret_cast<const float4*>(x)[i];
    ushort4 o;
    o.x = f2bf(v.x); o.y = f2bf(v.y); o.z = f2bf(v.z); o.w = f2bf(v.w);
    reinterpret_cast<ushort4*>(xb)[i] = o;
  }
}

// ---- transpose+cast: src [E][R][C] fp32 -> dst [E][C][R] bf16 ----
__global__ void transpose_cast_kernel(const float* __restrict__ src,
                                      unsigned short* __restrict__ dst, int R, int C) {
  __shared__ float tile[32][33];
  const int e = blockIdx.z;
  const int c0 = blockIdx.x * 32, r0 = blockIdx.y * 32;
  const float* s = src + (size_t)e * R * C;
  unsigned short* d = dst + (size_t)e * C * R;
  const int t = threadIdx.x;
  const int lr = t >> 3, lc4 = t & 7;
  float4 v = *reinterpret_cast<const float4*>(s + (size_t)(r0 + lr) * C + c0 + lc4 * 4);
  tile[lr][lc4 * 4 + 0] = v.x; tile[lr][lc4 * 4 + 1] = v.y;
  tile[lr][lc4 * 4 + 2] = v.z; tile[lr][lc4 * 4 + 3] = v.w;
  __syncthreads();
  ushort4 o;
  o.x = f2bf(tile[lc4 * 4 + 0][lr]); o.y = f2bf(tile[lc4 * 4 + 1][lr]);
  o.z = f2bf(tile[lc4 * 4 + 2][lr]); o.w = f2bf(tile[lc4 * 4 + 3][lr]);
  *reinterpret_cast<ushort4*>(d + (size_t)(c0 + lr) * R + r0 + lc4 * 4) = o;
}

// ---- gate: fp64 logits, top-2, renormalized weights ----
__global__ void gate_kernel(const float* __restrict__ x, const float* __restrict__ gw,
                            int* __restrict__ topk_i, float* __restrict__ topk_w,
                            int* __restrict__ counts) {
  const int wave = threadIdx.x >> 6, lane = threadIdx.x & 63;
  const int t = blockIdx.x * 4 + wave;
  const float* xr = x + (size_t)t * D_DIM;
  double acc[E_NUM] = {0, 0, 0, 0, 0, 0, 0, 0};
  for (int d = lane; d < D_DIM; d += 64) {
    double xv = (double)xr[d];
    const float* g = gw + d * E_NUM;
#pragma unroll
    for (int e = 0; e < E_NUM; e++) acc[e] += xv * (double)g[e];
  }
#pragma unroll
  for (int off = 32; off > 0; off >>= 1) {
#pragma unroll
    for (int e = 0; e < E_NUM; e++) acc[e] += __shfl_xor(acc[e], off, 64);
  }
  if (lane == 0) {
    int i0 = 0; double b0 = acc[0];
    for (int e = 1; e < E_NUM; e++) if (acc[e] > b0) { b0 = acc[e]; i0 = e; }
    int i1 = -1; double b1v = -1e300;
    for (int e = 0; e < E_NUM; e++) if (e != i0 && acc[e] > b1v) { b1v = acc[e]; i1 = e; }
    double w0 = 1.0 / (1.0 + exp(b1v - b0));
    topk_i[t * 2] = i0; topk_i[t * 2 + 1] = i1;
    topk_w[t * 2] = (float)w0; topk_w[t * 2 + 1] = (float)(1.0 - w0);
    atomicAdd(&counts[i0], 1); atomicAdd(&counts[i1], 1);
  }
}

__global__ void scan_kernel(const int* __restrict__ counts, int* __restrict__ offsets) {
  if (threadIdx.x == 0) {
    int s = 0;
    for (int e = 0; e < E_NUM; e++) { offsets[e] = s; s += counts[e]; }
  }
}

__global__ void build_lists_kernel(const int* __restrict__ topk_i, const int* __restrict__ offsets,
                                   int* __restrict__ cursors, int* __restrict__ rows,
                                   int* __restrict__ dest) {
  int t = blockIdx.x * blockDim.x + threadIdx.x;
  if (t >= T_TOK) return;
#pragma unroll
  for (int k = 0; k < 2; k++) {
    int e = topk_i[t * 2 + k];
    int slot = atomicAdd(&cursors[e], 1);
    int r = offsets[e] + slot;
    rows[r] = t;
    dest[t * 2 + k] = r;
  }
}

// ---- GEMM1: h = gelu(gather(x) @ w1T^T + b1), bf16 out ----
__global__ __launch_bounds__(256, 2) void gemm1_kernel(
    const unsigned short* __restrict__ xb, const unsigned short* __restrict__ w1T,
    const float* __restrict__ b1, const int* __restrict__ counts,
    const int* __restrict__ offsets, const int* __restrict__ rows,
    unsigned short* __restrict__ h) {
  const int e = blockIdx.z;
  const int cnt = counts[e];
  const int mt = blockIdx.y;
  if (mt * 128 >= cnt) return;
  const int nt = blockIdx.x;
  const int off = offsets[e];
  const int t = threadIdx.x;
  const int lane = t & 63, wave = t >> 6;
  const int wm = wave >> 1, wn = wave & 1;

  __shared__ __align__(16) unsigned short ldsA[2][4096];
  __shared__ __align__(16) unsigned short ldsB[2][4096];

  const int tr = t >> 2, tc = t & 3;
  const int a0 = mt * 128 + tr;
  const int a1 = a0 + 64;
  const int g0 = rows[off + min(a0, cnt - 1)];
  const int g1 = rows[off + min(a1, cnt - 1)];
  const unsigned short* aptr0 = xb + (size_t)g0 * D_DIM + tc * 8;
  const unsigned short* aptr1 = xb + (size_t)g1 * D_DIM + tc * 8;
  const unsigned short* wb = w1T + (size_t)e * F_DIM * D_DIM;
  const unsigned short* bptr0 = wb + (size_t)(nt * 128 + tr) * D_DIM + tc * 8;
  const unsigned short* bptr1 = bptr0 + (size_t)64 * D_DIM;

  f32x4 acc[4][4];
  const f32x4 z = {0.f, 0.f, 0.f, 0.f};
#pragma unroll
  for (int i = 0; i < 4; i++)
#pragma unroll
    for (int j = 0; j < 4; j++) acc[i][j] = z;

  auto stage = [&](int buf, int kt) {
    const int kb = kt * 32;
    gll16(aptr0 + kb, &ldsA[buf][wave * 512]);
    gll16(aptr1 + kb, &ldsA[buf][2048 + wave * 512]);
    gll16(bptr0 + kb, &ldsB[buf][wave * 512]);
    gll16(bptr1 + kb, &ldsB[buf][2048 + wave * 512]);
  };
  stage(0, 0);
  asm volatile("s_waitcnt vmcnt(0)" ::: "memory");
  __syncthreads();

  const int rA = wm * 64 + (lane & 15);
  const int rB = wn * 64 + (lane & 15);
  const int ko = (lane >> 4) * 8;
  const int NK = D_DIM / 32;

  for (int kt = 0; kt < NK; ++kt) {
    const int cur = kt & 1;
    if (kt + 1 < NK) stage(cur ^ 1, kt + 1);
    bf16x8 af[4], bfr[4];
#pragma unroll
    for (int mf = 0; mf < 4; mf++)
      af[mf] = *(const bf16x8*)&ldsA[cur][(rA + mf * 16) * 32 + ko];
#pragma unroll
    for (int nf = 0; nf < 4; nf++)
      bfr[nf] = *(const bf16x8*)&ldsB[cur][(rB + nf * 16) * 32 + ko];
#pragma unroll
    for (int mf = 0; mf < 4; mf++)
#pragma unroll
      for (int nf = 0; nf < 4; nf++)
        acc[mf][nf] = __builtin_amdgcn_mfma_f32_16x16x32_bf16(af[mf], bfr[nf], acc[mf][nf], 0, 0, 0);
    asm volatile("s_waitcnt vmcnt(0)" ::: "memory");
    __syncthreads();
  }

  const int valid = cnt - mt * 128;
  const int col = lane & 15;
  const int rq = (lane >> 4) * 4;
#pragma unroll
  for (int nf = 0; nf < 4; nf++) {
    const int c = nt * 128 + wn * 64 + nf * 16 + col;
    const float bias = b1[(size_t)e * F_DIM + c];
#pragma unroll
    for (int mf = 0; mf < 4; mf++) {
#pragma unroll
      for (int r4 = 0; r4 < 4; r4++) {
        int rloc = wm * 64 + mf * 16 + rq + r4;
        if (rloc < valid) {
          float v = acc[mf][nf][r4] + bias;
          v = 0.5f * v * (1.0f + erff(v * 0.7071067811865475f));
          h[(size_t)(off + mt * 128 + rloc) * F_DIM + c] = f2bf(v);
        }
      }
    }
  }
}

// ---- GEMM2: y = h @ w2T^T + b2, fp32 out ----
__global__ __launch_bounds__(256, 2) void gemm2_kernel(
    const unsigned short* __restrict__ h, const unsigned short* __restrict__ w2T,
    const float* __restrict__ b2, const int* __restrict__ counts,
    const int* __restrict__ offsets, float* __restrict__ y) {
  const int e = blockIdx.z;
  const int cnt = counts[e];
  const int mt = blockIdx.y;
  if (mt * 128 >= cnt) return;
  const int nt = blockIdx.x;
  const int off = offsets[e];
  const int t = threadIdx.x;
  const int lane = t & 63, wave = t >> 6;
  const int wm = wave >> 1, wn = wave & 1;

  __shared__ __align__(16) unsigned short ldsA[2][4096];
  __shared__ __align__(16) unsigned short ldsB[2][4096];

  const int tr = t >> 2, tc = t & 3;
  const int l0 = min(mt * 128 + tr, cnt - 1);
  const int l1 = min(mt * 128 + 64 + tr, cnt - 1);
  const unsigned short* aptr0 = h + (size_t)(off + l0) * F_DIM + tc * 8;
  const unsigned short* aptr1 = h + (size_t)(off + l1) * F_DIM + tc * 8;
  const unsigned short* wb = w2T + (size_t)e * D_DIM * F_DIM;
  const unsigned short* bptr0 = wb + (size_t)(nt * 128 + tr) * F_DIM + tc * 8;
  const unsigned short* bptr1 = bptr0 + (size_t)64 * F_DIM;

  f32x4 acc[4][4];
  const f32x4 z = {0.f, 0.f, 0.f, 0.f};
#pragma unroll
  for (int i = 0; i < 4; i++)
#pragma unroll
    for (int j = 0; j < 4; j++) acc[i][j] = z;

  auto stage = [&](int buf, int kt) {
    const int kb = kt * 32;
    gll16(aptr0 + kb, &ldsA[buf][wave * 512]);
    gll16(aptr1 + kb, &ldsA[buf][2048 + wave * 512]);
    gll16(bptr0 + kb, &ldsB[buf][wave * 512]);
    gll16(bptr1 + kb, &ldsB[buf][2048 + wave * 512]);
  };
  stage(0, 0);
  asm volatile("s_waitcnt vmcnt(0)" ::: "memory");
  __syncthreads();

  const int rA = wm * 64 + (lane & 15);
  const int rB = wn * 64 + (lane & 15);
  const int ko = (lane >> 4) * 8;
  const int NK = F_DIM / 32;

  for (int kt = 0; kt < NK; ++kt) {
    const int cur = kt & 1;
    if (kt + 1 < NK) stage(cur ^ 1, kt + 1);
    bf16x8 af[4], bfr[4];
#pragma unroll
    for (int mf = 0; mf < 4; mf++)
      af[mf] = *(const bf16x8*)&ldsA[cur][(rA + mf * 16) * 32 + ko];
#pragma unroll
    for (int nf = 0; nf < 4; nf++)
      bfr[nf] = *(const bf16x8*)&ldsB[cur][(rB + nf * 16) * 32 + ko];
#pragma unroll
    for (int mf = 0; mf < 4; mf++)
#pragma unroll
      for (int nf = 0; nf < 4; nf++)
        acc[mf][nf] = __builtin_amdgcn_mfma_f32_16x16x32_bf16(af[mf], bfr[nf], acc[mf][nf], 0, 0, 0);
    asm volatile("s_waitcnt vmcnt(0)" ::: "memory");
    __syncthreads();
  }

  const int valid = cnt - mt * 128;
  const int col = lane & 15;
  const int rq = (lane >> 4) * 4;
#pragma unroll
  for (int nf = 0; nf < 4; nf++) {
    const int c = nt * 128 + wn * 64 + nf * 16 + col;
    const float bias = b2[(size_t)e * D_DIM + c];
#pragma unroll
    for (int mf = 0; mf < 4; mf++) {
#pragma unroll
      for (int r4 = 0; r4 < 4; r4++) {
        int rloc = wm * 64 + mf * 16 + rq + r4;
        if (rloc < valid)
          y[(size_t)(off + mt * 128 + rloc) * D_DIM + c] = acc[mf][nf][r4] + bias;
      }
    }
  }
}

// ---- combine: out[t] = w0*y[r0] + w1*y[r1] ----
__global__ void combine_kernel(const float* __restrict__ y, const int* __restrict__ dest,
                               const float* __restrict__ tw, float* __restrict__ out) {
  const int n4 = T_TOK * D_DIM / 4;
  for (int i = blockIdx.x * blockDim.x + threadIdx.x; i < n4; i += gridDim.x * blockDim.x) {
    int tok = i >> 8;    // D/4 = 256
    int c = i & 255;
    int r0 = dest[2 * tok], r1 = dest[2 * tok + 1];
    float w0 = tw[2 * tok], w1 = tw[2 * tok + 1];
    float4 a = reinterpret_cast<const float4*>(y + (size_t)r0 * D_DIM)[c];
    float4 b = reinterpret_cast<const float4*>(y + (size_t)r1 * D_DIM)[c];
    float4 o;
    o.x = w0 * a.x + w1 * b.x; o.y = w0 * a.y + w1 * b.y;
    o.z = w0 * a.z + w1 * b.z; o.w = w0 * a.w + w1 * b.w;
    reinterpret_cast<float4*>(out + (size_t)tok * D_DIM)[c] = o;
  }
}

extern "C" void kernel_launch(void* const* d_in, const int* in_sizes, int n_in,
                              void* d_out, int out_size, void* d_ws, size_t ws_size,
                              hipStream_t stream) {
  (void)in_sizes; (void)n_in; (void)out_size; (void)ws_size;
  const float* x = (const float*)d_in[0];
  const float* gw = (const float*)d_in[1];
  const float* w1 = (const float*)d_in[2];
  const float* b1 = (const float*)d_in[3];
  const float* w2 = (const float*)d_in[4];
  const float* b2 = (const float*)d_in[5];
  float* out = (float*)d_out;
  char* ws = (char*)d_ws;

  int* counts = (int*)(ws + WS_COUNTS);
  int* cursors = (int*)(ws + WS_CURSORS);
  int* offsets = (int*)(ws + WS_OFFSETS);
  int* topk_i = (int*)(ws + WS_TOPKI);
  float* topk_w = (float*)(ws + WS_TOPKW);
  int* rows = (int*)(ws + WS_ROWS);
  int* dest = (int*)(ws + WS_DEST);
  unsigned short* xb = (unsigned short*)(ws + WS_XB);
  unsigned short* w1T = (unsigned short*)(ws + WS_W1T);
  unsigned short* w2T = (unsigned short*)(ws + WS_W2T);
  unsigned short* hbuf = (unsigned short*)(ws + WS_H);
  float* ybuf = (float*)(ws + WS_Y);

  hipMemsetAsync(ws, 0, 4096, stream);
  cast_x_kernel<<<2048, 256, 0, stream>>>(x, xb);
  transpose_cast_kernel<<<dim3(F_DIM / 32, D_DIM / 32, E_NUM), 256, 0, stream>>>(w1, w1T, D_DIM, F_DIM);
  transpose_cast_kernel<<<dim3(D_DIM / 32, F_DIM / 32, E_NUM), 256, 0, stream>>>(w2, w2T, F_DIM, D_DIM);
  gate_kernel<<<T_TOK / 4, 256, 0, stream>>>(x, gw, topk_i, topk_w, counts);
  scan_kernel<<<1, 64, 0, stream>>>(counts, offsets);
  build_lists_kernel<<<T_TOK / 256, 256, 0, stream>>>(topk_i, offsets, cursors, rows, dest);
  gemm1_kernel<<<dim3(F_DIM / 128, 32, E_NUM), 256, 0, stream>>>(xb, w1T, b1, counts, offsets, rows, hbuf);
  gemm2_kernel<<<dim3(D_DIM / 128, 32, E_NUM), 256, 0, stream>>>(hbuf, w2T, b2, counts, offsets, ybuf);
  combine_kernel<<<2048, 256, 0, stream>>>(ybuf, dest, topk_w, out);
}

// Round 4
// 702.593 us; speedup vs baseline: 1.1174x; 1.1174x over previous
//
#include <hip/hip_runtime.h>
#include <hip/hip_bf16.h>
#include <stdint.h>

#define T_TOK 4096
#define D_DIM 1024
#define F_DIM 4096
#define E_NUM 8
#define NROUTED (T_TOK * 2)

typedef __attribute__((ext_vector_type(8))) __bf16 bf16x8;
typedef __attribute__((ext_vector_type(4))) float f32x4;
typedef __attribute__((ext_vector_type(8))) unsigned short u16x8;

// ---- workspace layout (bytes) ----
#define WS_COUNTS 0
#define WS_CURSORS 64
#define WS_OFFSETS 128
#define WS_TOPKI 4096
#define WS_TOPKW (WS_TOPKI + NROUTED * 4)
#define WS_ROWS (WS_TOPKW + NROUTED * 4)
#define WS_DEST (WS_ROWS + NROUTED * 4)
#define WS_XB ((size_t)1 << 20)
#define WS_W1T (WS_XB + (size_t)T_TOK * D_DIM * 2)
#define WS_W2T (WS_W1T + (size_t)E_NUM * D_DIM * F_DIM * 2)
#define WS_H (WS_W2T + (size_t)E_NUM * D_DIM * F_DIM * 2)
#define WS_Y (WS_H + (size_t)NROUTED * F_DIM * 2)

__device__ __forceinline__ unsigned short f2bf(float f) {
  uint32_t u = __float_as_uint(f);
  uint32_t r = (u + 0x7FFFu + ((u >> 16) & 1u)) >> 16;  // RNE
  return (unsigned short)r;
}

__device__ __forceinline__ void gll16(const void* g, void* l) {
  __builtin_amdgcn_global_load_lds(
      (__attribute__((address_space(1))) void*)(void*)(g),
      (__attribute__((address_space(3))) void*)(l), 16, 0, 0);
}

// ---- cast x fp32 -> bf16 ----
__global__ void cast_x_kernel(const float* __restrict__ x, unsigned short* __restrict__ xb) {
  int n4 = T_TOK * D_DIM / 4;
  for (int i = blockIdx.x * blockDim.x + threadIdx.x; i < n4; i += gridDim.x * blockDim.x) {
    float4 v = reinterpret_cast<const float4*>(x)[i];
    ushort4 o;
    o.x = f2bf(v.x); o.y = f2bf(v.y); o.z = f2bf(v.z); o.w = f2bf(v.w);
    reinterpret_cast<ushort4*>(xb)[i] = o;
  }
}

// ---- transpose+cast: src [E][R][C] fp32 -> dst [E][C][R] bf16, 64x64 tiles ----
__global__ void transpose_cast_kernel(const float* __restrict__ src,
                                      unsigned short* __restrict__ dst, int R, int C) {
  __shared__ float tile[64][65];
  const int e = blockIdx.z;
  const int c0 = blockIdx.x * 64, r0 = blockIdx.y * 64;
  const float* s = src + (size_t)e * R * C;
  unsigned short* d = dst + (size_t)e * C * R;
  const int t = threadIdx.x;
  const int lr = t >> 4, lc = (t & 15) * 4;
#pragma unroll
  for (int rr = 0; rr < 4; rr++) {
    const int r = lr + rr * 16;
    float4 v = *reinterpret_cast<const float4*>(s + (size_t)(r0 + r) * C + c0 + lc);
    tile[r][lc + 0] = v.x; tile[r][lc + 1] = v.y;
    tile[r][lc + 2] = v.z; tile[r][lc + 3] = v.w;
  }
  __syncthreads();
  const int wc = t >> 3, wr = (t & 7) * 8;
#pragma unroll
  for (int cc = 0; cc < 2; cc++) {
    const int c = wc + cc * 32;
    u16x8 o;
#pragma unroll
    for (int k = 0; k < 8; k++) o[k] = f2bf(tile[wr + k][c]);
    *reinterpret_cast<u16x8*>(d + (size_t)(c0 + c) * R + r0 + wr) = o;
  }
}

// ---- gate: fp64 logits, top-2, renormalized weights ----
__global__ void gate_kernel(const float* __restrict__ x, const float* __restrict__ gw,
                            int* __restrict__ topk_i, float* __restrict__ topk_w,
                            int* __restrict__ counts) {
  const int wave = threadIdx.x >> 6, lane = threadIdx.x & 63;
  const int t = blockIdx.x * 4 + wave;
  const float* xr = x + (size_t)t * D_DIM;
  double acc[E_NUM] = {0, 0, 0, 0, 0, 0, 0, 0};
  for (int d = lane; d < D_DIM; d += 64) {
    double xv = (double)xr[d];
    const float* g = gw + d * E_NUM;
#pragma unroll
    for (int e = 0; e < E_NUM; e++) acc[e] += xv * (double)g[e];
  }
#pragma unroll
  for (int off = 32; off > 0; off >>= 1) {
#pragma unroll
    for (int e = 0; e < E_NUM; e++) acc[e] += __shfl_xor(acc[e], off, 64);
  }
  if (lane == 0) {
    int i0 = 0; double b0 = acc[0];
    for (int e = 1; e < E_NUM; e++) if (acc[e] > b0) { b0 = acc[e]; i0 = e; }
    int i1 = -1; double b1v = -1e300;
    for (int e = 0; e < E_NUM; e++) if (e != i0 && acc[e] > b1v) { b1v = acc[e]; i1 = e; }
    double w0 = 1.0 / (1.0 + exp(b1v - b0));
    topk_i[t * 2] = i0; topk_i[t * 2 + 1] = i1;
    topk_w[t * 2] = (float)w0; topk_w[t * 2 + 1] = (float)(1.0 - w0);
    atomicAdd(&counts[i0], 1); atomicAdd(&counts[i1], 1);
  }
}

__global__ void scan_kernel(const int* __restrict__ counts, int* __restrict__ offsets) {
  if (threadIdx.x == 0) {
    int s = 0;
    for (int e = 0; e < E_NUM; e++) { offsets[e] = s; s += counts[e]; }
  }
}

__global__ void build_lists_kernel(const int* __restrict__ topk_i, const int* __restrict__ offsets,
                                   int* __restrict__ cursors, int* __restrict__ rows,
                                   int* __restrict__ dest) {
  int t = blockIdx.x * blockDim.x + threadIdx.x;
  if (t >= T_TOK) return;
#pragma unroll
  for (int k = 0; k < 2; k++) {
    int e = topk_i[t * 2 + k];
    int slot = atomicAdd(&cursors[e], 1);
    int r = offsets[e] + slot;
    rows[r] = t;
    dest[t * 2 + k] = r;
  }
}

// ---- GEMM1: h = gelu(gather(x) @ w1T^T + b1), bf16 out ----
// 128x128 tile, 4 waves, 3-slot LDS pipeline w/ counted vmcnt, XCD-chunked grid.
__global__ __launch_bounds__(256, 3) void gemm1_kernel(
    const unsigned short* __restrict__ xb, const unsigned short* __restrict__ w1T,
    const float* __restrict__ b1, const int* __restrict__ counts,
    const int* __restrict__ offsets, const int* __restrict__ rows,
    unsigned short* __restrict__ h) {
  // grid = 32(nt) * 32(mt) * 8(e) = 8192; chunked XCD swizzle (nwg%8==0)
  const int hw = blockIdx.x;
  const int lid = (hw & 7) * (8192 >> 3) + (hw >> 3);
  const int nt = lid & 31;
  const int mt = (lid >> 5) & 31;
  const int e = lid >> 10;

  const int cnt = counts[e];
  if (mt * 128 >= cnt) return;
  const int off = offsets[e];
  const int t = threadIdx.x;
  const int lane = t & 63, wave = t >> 6;
  const int wm = wave >> 1, wn = wave & 1;

  __shared__ __align__(16) unsigned short ldsA[3][4096];
  __shared__ __align__(16) unsigned short ldsB[3][4096];

  const int tr = t >> 2, tc = t & 3;
  const int a0 = mt * 128 + tr;
  const int g0 = rows[off + min(a0, cnt - 1)];
  const int g1 = rows[off + min(a0 + 64, cnt - 1)];
  const unsigned short* aptr0 = xb + (size_t)g0 * D_DIM + tc * 8;
  const unsigned short* aptr1 = xb + (size_t)g1 * D_DIM + tc * 8;
  const unsigned short* wb = w1T + (size_t)e * F_DIM * D_DIM;
  const unsigned short* bptr0 = wb + (size_t)(nt * 128 + tr) * D_DIM + tc * 8;
  const unsigned short* bptr1 = bptr0 + (size_t)64 * D_DIM;

  // preload bias (keeps loop free of extra VMEM so vmcnt counting is exact)
  const int col = lane & 15;
  float bias_v[4];
#pragma unroll
  for (int nf = 0; nf < 4; nf++)
    bias_v[nf] = b1[(size_t)e * F_DIM + nt * 128 + wn * 64 + nf * 16 + col];

  f32x4 acc[4][4];
  const f32x4 z = {0.f, 0.f, 0.f, 0.f};
#pragma unroll
  for (int i = 0; i < 4; i++)
#pragma unroll
    for (int j = 0; j < 4; j++) acc[i][j] = z;

  auto stage = [&](int buf, int kt) {
    const int kb = kt * 32;
    gll16(aptr0 + kb, &ldsA[buf][wave * 512]);
    gll16(aptr1 + kb, &ldsA[buf][2048 + wave * 512]);
    gll16(bptr0 + kb, &ldsB[buf][wave * 512]);
    gll16(bptr1 + kb, &ldsB[buf][2048 + wave * 512]);
  };

  asm volatile("s_waitcnt vmcnt(0)" ::: "memory");  // clean slate for counting
  stage(0, 0);
  stage(1, 1);

  const int rA = wm * 64 + (lane & 15);
  const int rB = wn * 64 + (lane & 15);
  const int ko = (lane >> 4) * 8;
  const int NK = D_DIM / 32;  // 32

  for (int kt = 0; kt < NK; ++kt) {
    const int cur = kt - (kt / 3) * 3;  // kt % 3
    if (kt + 2 < NK) {
      stage((kt + 2) - ((kt + 2) / 3) * 3, kt + 2);
      asm volatile("s_waitcnt vmcnt(8)" ::: "memory");
    } else if (kt + 2 == NK) {
      asm volatile("s_waitcnt vmcnt(4)" ::: "memory");
    } else {
      asm volatile("s_waitcnt vmcnt(0)" ::: "memory");
    }
    __builtin_amdgcn_s_barrier();
    bf16x8 af[4], bfr[4];
#pragma unroll
    for (int mf = 0; mf < 4; mf++)
      af[mf] = *(const bf16x8*)&ldsA[cur][(rA + mf * 16) * 32 + ko];
#pragma unroll
    for (int nf = 0; nf < 4; nf++)
      bfr[nf] = *(const bf16x8*)&ldsB[cur][(rB + nf * 16) * 32 + ko];
#pragma unroll
    for (int mf = 0; mf < 4; mf++)
#pragma unroll
      for (int nf = 0; nf < 4; nf++)
        acc[mf][nf] = __builtin_amdgcn_mfma_f32_16x16x32_bf16(af[mf], bfr[nf], acc[mf][nf], 0, 0, 0);
    __builtin_amdgcn_s_barrier();
  }

  const int valid = cnt - mt * 128;
  const int rq = (lane >> 4) * 4;
#pragma unroll
  for (int nf = 0; nf < 4; nf++) {
    const int c = nt * 128 + wn * 64 + nf * 16 + col;
    const float bias = bias_v[nf];
#pragma unroll
    for (int mf = 0; mf < 4; mf++) {
#pragma unroll
      for (int r4 = 0; r4 < 4; r4++) {
        int rloc = wm * 64 + mf * 16 + rq + r4;
        if (rloc < valid) {
          float v = acc[mf][nf][r4] + bias;
          v = 0.5f * v * (1.0f + erff(v * 0.7071067811865475f));
          h[(size_t)(off + mt * 128 + rloc) * F_DIM + c] = f2bf(v);
        }
      }
    }
  }
}

// ---- GEMM2: y = h @ w2T^T + b2, fp32 out ----
__global__ __launch_bounds__(256, 3) void gemm2_kernel(
    const unsigned short* __restrict__ h, const unsigned short* __restrict__ w2T,
    const float* __restrict__ b2, const int* __restrict__ counts,
    const int* __restrict__ offsets, float* __restrict__ y) {
  // grid = 8(nt) * 32(mt) * 8(e) = 2048; chunked XCD swizzle
  const int hw = blockIdx.x;
  const int lid = (hw & 7) * (2048 >> 3) + (hw >> 3);
  const int nt = lid & 7;
  const int mt = (lid >> 3) & 31;
  const int e = lid >> 8;

  const int cnt = counts[e];
  if (mt * 128 >= cnt) return;
  const int off = offsets[e];
  const int t = threadIdx.x;
  const int lane = t & 63, wave = t >> 6;
  const int wm = wave >> 1, wn = wave & 1;

  __shared__ __align__(16) unsigned short ldsA[3][4096];
  __shared__ __align__(16) unsigned short ldsB[3][4096];

  const int tr = t >> 2, tc = t & 3;
  const int l0 = min(mt * 128 + tr, cnt - 1);
  const int l1 = min(mt * 128 + 64 + tr, cnt - 1);
  const unsigned short* aptr0 = h + (size_t)(off + l0) * F_DIM + tc * 8;
  const unsigned short* aptr1 = h + (size_t)(off + l1) * F_DIM + tc * 8;
  const unsigned short* wb = w2T + (size_t)e * D_DIM * F_DIM;
  const unsigned short* bptr0 = wb + (size_t)(nt * 128 + tr) * F_DIM + tc * 8;
  const unsigned short* bptr1 = bptr0 + (size_t)64 * F_DIM;

  const int col = lane & 15;
  float bias_v[4];
#pragma unroll
  for (int nf = 0; nf < 4; nf++)
    bias_v[nf] = b2[(size_t)e * D_DIM + nt * 128 + wn * 64 + nf * 16 + col];

  f32x4 acc[4][4];
  const f32x4 z = {0.f, 0.f, 0.f, 0.f};
#pragma unroll
  for (int i = 0; i < 4; i++)
#pragma unroll
    for (int j = 0; j < 4; j++) acc[i][j] = z;

  auto stage = [&](int buf, int kt) {
    const int kb = kt * 32;
    gll16(aptr0 + kb, &ldsA[buf][wave * 512]);
    gll16(aptr1 + kb, &ldsA[buf][2048 + wave * 512]);
    gll16(bptr0 + kb, &ldsB[buf][wave * 512]);
    gll16(bptr1 + kb, &ldsB[buf][2048 + wave * 512]);
  };

  asm volatile("s_waitcnt vmcnt(0)" ::: "memory");
  stage(0, 0);
  stage(1, 1);

  const int rA = wm * 64 + (lane & 15);
  const int rB = wn * 64 + (lane & 15);
  const int ko = (lane >> 4) * 8;
  const int NK = F_DIM / 32;  // 128

  for (int kt = 0; kt < NK; ++kt) {
    const int cur = kt - (kt / 3) * 3;
    if (kt + 2 < NK) {
      stage((kt + 2) - ((kt + 2) / 3) * 3, kt + 2);
      asm volatile("s_waitcnt vmcnt(8)" ::: "memory");
    } else if (kt + 2 == NK) {
      asm volatile("s_waitcnt vmcnt(4)" ::: "memory");
    } else {
      asm volatile("s_waitcnt vmcnt(0)" ::: "memory");
    }
    __builtin_amdgcn_s_barrier();
    bf16x8 af[4], bfr[4];
#pragma unroll
    for (int mf = 0; mf < 4; mf++)
      af[mf] = *(const bf16x8*)&ldsA[cur][(rA + mf * 16) * 32 + ko];
#pragma unroll
    for (int nf = 0; nf < 4; nf++)
      bfr[nf] = *(const bf16x8*)&ldsB[cur][(rB + nf * 16) * 32 + ko];
#pragma unroll
    for (int mf = 0; mf < 4; mf++)
#pragma unroll
      for (int nf = 0; nf < 4; nf++)
        acc[mf][nf] = __builtin_amdgcn_mfma_f32_16x16x32_bf16(af[mf], bfr[nf], acc[mf][nf], 0, 0, 0);
    __builtin_amdgcn_s_barrier();
  }

  const int valid = cnt - mt * 128;
  const int rq = (lane >> 4) * 4;
#pragma unroll
  for (int nf = 0; nf < 4; nf++) {
    const int c = nt * 128 + wn * 64 + nf * 16 + col;
    const float bias = bias_v[nf];
#pragma unroll
    for (int mf = 0; mf < 4; mf++) {
#pragma unroll
      for (int r4 = 0; r4 < 4; r4++) {
        int rloc = wm * 64 + mf * 16 + rq + r4;
        if (rloc < valid)
          y[(size_t)(off + mt * 128 + rloc) * D_DIM + c] = acc[mf][nf][r4] + bias;
      }
    }
  }
}

// ---- combine: out[t] = w0*y[r0] + w1*y[r1] ----
__global__ void combine_kernel(const float* __restrict__ y, const int* __restrict__ dest,
                               const float* __restrict__ tw, float* __restrict__ out) {
  const int n4 = T_TOK * D_DIM / 4;
  for (int i = blockIdx.x * blockDim.x + threadIdx.x; i < n4; i += gridDim.x * blockDim.x) {
    int tok = i >> 8;  // D/4 = 256
    int c = i & 255;
    int r0 = dest[2 * tok], r1 = dest[2 * tok + 1];
    float w0 = tw[2 * tok], w1 = tw[2 * tok + 1];
    float4 a = reinterpret_cast<const float4*>(y + (size_t)r0 * D_DIM)[c];
    float4 b = reinterpret_cast<const float4*>(y + (size_t)r1 * D_DIM)[c];
    float4 o;
    o.x = w0 * a.x + w1 * b.x; o.y = w0 * a.y + w1 * b.y;
    o.z = w0 * a.z + w1 * b.z; o.w = w0 * a.w + w1 * b.w;
    reinterpret_cast<float4*>(out + (size_t)tok * D_DIM)[c] = o;
  }
}

extern "C" void kernel_launch(void* const* d_in, const int* in_sizes, int n_in,
                              void* d_out, int out_size, void* d_ws, size_t ws_size,
                              hipStream_t stream) {
  (void)in_sizes; (void)n_in; (void)out_size; (void)ws_size;
  const float* x = (const float*)d_in[0];
  const float* gw = (const float*)d_in[1];
  const float* w1 = (const float*)d_in[2];
  const float* b1 = (const float*)d_in[3];
  const float* w2 = (const float*)d_in[4];
  const float* b2 = (const float*)d_in[5];
  float* out = (float*)d_out;
  char* ws = (char*)d_ws;

  int* counts = (int*)(ws + WS_COUNTS);
  int* cursors = (int*)(ws + WS_CURSORS);
  int* offsets = (int*)(ws + WS_OFFSETS);
  int* topk_i = (int*)(ws + WS_TOPKI);
  float* topk_w = (float*)(ws + WS_TOPKW);
  int* rows = (int*)(ws + WS_ROWS);
  int* dest = (int*)(ws + WS_DEST);
  unsigned short* xb = (unsigned short*)(ws + WS_XB);
  unsigned short* w1T = (unsigned short*)(ws + WS_W1T);
  unsigned short* w2T = (unsigned short*)(ws + WS_W2T);
  unsigned short* hbuf = (unsigned short*)(ws + WS_H);
  float* ybuf = (float*)(ws + WS_Y);

  hipMemsetAsync(ws, 0, 4096, stream);
  cast_x_kernel<<<2048, 256, 0, stream>>>(x, xb);
  gate_kernel<<<T_TOK / 4, 256, 0, stream>>>(x, gw, topk_i, topk_w, counts);
  scan_kernel<<<1, 64, 0, stream>>>(counts, offsets);
  build_lists_kernel<<<T_TOK / 256, 256, 0, stream>>>(topk_i, offsets, cursors, rows, dest);
  // w1T right before gemm1, w2T right before gemm2: keep them L3-hot.
  transpose_cast_kernel<<<dim3(F_DIM / 64, D_DIM / 64, E_NUM), 256, 0, stream>>>(w1, w1T, D_DIM, F_DIM);
  gemm1_kernel<<<8192, 256, 0, stream>>>(xb, w1T, b1, counts, offsets, rows, hbuf);
  transpose_cast_kernel<<<dim3(D_DIM / 64, F_DIM / 64, E_NUM), 256, 0, stream>>>(w2, w2T, F_DIM, D_DIM);
  gemm2_kernel<<<2048, 256, 0, stream>>>(hbuf, w2T, b2, counts, offsets, ybuf);
  combine_kernel<<<2048, 256, 0, stream>>>(ybuf, dest, topk_w, out);
}

// Round 6
// 667.406 us; speedup vs baseline: 1.1763x; 1.0527x over previous
//
#include <hip/hip_runtime.h>
#include <hip/hip_bf16.h>
#include <stdint.h>

#define T_TOK 4096
#define D_DIM 1024
#define F_DIM 4096
#define E_NUM 8
#define NROUTED (T_TOK * 2)

typedef __attribute__((ext_vector_type(8))) __bf16 bf16x8;
typedef __attribute__((ext_vector_type(4))) float f32x4;
typedef __attribute__((ext_vector_type(8))) unsigned short u16x8;

// ---- workspace layout (bytes) ----
#define WS_COUNTS 0
#define WS_OFFSETS 128
#define WS_TOPKI 4096
#define WS_TOPKW (WS_TOPKI + NROUTED * 4)
#define WS_ROWS (WS_TOPKW + NROUTED * 4)
#define WS_DEST (WS_ROWS + NROUTED * 4)
#define WS_XB ((size_t)1 << 20)
#define WS_W1T (WS_XB + (size_t)T_TOK * D_DIM * 2)
#define WS_W2T (WS_W1T + (size_t)E_NUM * D_DIM * F_DIM * 2)
#define WS_H (WS_W2T + (size_t)E_NUM * D_DIM * F_DIM * 2)
#define WS_Y (WS_H + (size_t)NROUTED * F_DIM * 2)

__device__ __forceinline__ unsigned short f2bf(float f) {
  uint32_t u = __float_as_uint(f);
  uint32_t r = (u + 0x7FFFu + ((u >> 16) & 1u)) >> 16;  // RNE
  return (unsigned short)r;
}

__device__ __forceinline__ void gll16(const void* g, void* l) {
  __builtin_amdgcn_global_load_lds(
      (__attribute__((address_space(1))) void*)(void*)(g),
      (__attribute__((address_space(3))) void*)(l), 16, 0, 0);
}

// ---- transpose+cast: src [E][R][C] fp32 -> dst [E][C][R] bf16, 64x64 tiles ----
__global__ void transpose_cast_kernel(const float* __restrict__ src,
                                      unsigned short* __restrict__ dst, int R, int C) {
  __shared__ float tile[64][65];
  const int e = blockIdx.z;
  const int c0 = blockIdx.x * 64, r0 = blockIdx.y * 64;
  const float* s = src + (size_t)e * R * C;
  unsigned short* d = dst + (size_t)e * C * R;
  const int t = threadIdx.x;
  const int lr = t >> 4, lc = (t & 15) * 4;
#pragma unroll
  for (int rr = 0; rr < 4; rr++) {
    const int r = lr + rr * 16;
    float4 v = *reinterpret_cast<const float4*>(s + (size_t)(r0 + r) * C + c0 + lc);
    tile[r][lc + 0] = v.x; tile[r][lc + 1] = v.y;
    tile[r][lc + 2] = v.z; tile[r][lc + 3] = v.w;
  }
  __syncthreads();
  const int wc = t >> 3, wr = (t & 7) * 8;
#pragma unroll
  for (int cc = 0; cc < 2; cc++) {
    const int c = wc + cc * 32;
    u16x8 o;
#pragma unroll
    for (int k = 0; k < 8; k++) o[k] = f2bf(tile[wr + k][c]);
    *reinterpret_cast<u16x8*>(d + (size_t)(c0 + c) * R + r0 + wr) = o;
  }
}

// ---- gate: fp64 logits, top-2, renorm weights; fused vectorized x->bf16 cast ----
__global__ void gate_kernel(const float* __restrict__ x, const float* __restrict__ gw,
                            unsigned short* __restrict__ xb,
                            int* __restrict__ topk_i, float* __restrict__ topk_w,
                            int* __restrict__ counts) {
  const int wave = threadIdx.x >> 6, lane = threadIdx.x & 63;
  const int t = blockIdx.x * 4 + wave;
  const float* xr = x + (size_t)t * D_DIM;
  unsigned short* xo = xb + (size_t)t * D_DIM;
  double acc[E_NUM] = {0, 0, 0, 0, 0, 0, 0, 0};
#pragma unroll
  for (int it = 0; it < D_DIM / 256; it++) {
    const int d0 = it * 256 + lane * 4;
    float4 v = *reinterpret_cast<const float4*>(xr + d0);
    ushort4 o;
    o.x = f2bf(v.x); o.y = f2bf(v.y); o.z = f2bf(v.z); o.w = f2bf(v.w);
    *reinterpret_cast<ushort4*>(xo + d0) = o;
    const float* g = gw + (size_t)d0 * E_NUM;
    float xv[4] = {v.x, v.y, v.z, v.w};
#pragma unroll
    for (int j = 0; j < 4; j++)
#pragma unroll
      for (int e = 0; e < E_NUM; e++) acc[e] += (double)xv[j] * (double)g[j * E_NUM + e];
  }
#pragma unroll
  for (int off = 32; off > 0; off >>= 1) {
#pragma unroll
    for (int e = 0; e < E_NUM; e++) acc[e] += __shfl_xor(acc[e], off, 64);
  }
  if (lane == 0) {
    int i0 = 0; double b0 = acc[0];
    for (int e = 1; e < E_NUM; e++) if (acc[e] > b0) { b0 = acc[e]; i0 = e; }
    int i1 = -1; double b1v = -1e300;
    for (int e = 0; e < E_NUM; e++) if (e != i0 && acc[e] > b1v) { b1v = acc[e]; i1 = e; }
    double w0 = 1.0 / (1.0 + exp(b1v - b0));
    topk_i[t * 2] = i0; topk_i[t * 2 + 1] = i1;
    topk_w[t * 2] = (float)w0; topk_w[t * 2 + 1] = (float)(1.0 - w0);
    atomicAdd(&counts[i0], 1); atomicAdd(&counts[i1], 1);
  }
}

// ---- deterministic token-ordered compaction: one wave per expert ----
__global__ void compact_kernel(const int* __restrict__ topk_i, const int* __restrict__ counts,
                               int* __restrict__ offsets, int* __restrict__ rows,
                               int* __restrict__ dest) {
  const int e = blockIdx.x;
  const int lane = threadIdx.x;
  int offv = 0;
  for (int i = 0; i < e; i++) offv += counts[i];
  if (lane == 0) offsets[e] = offv;
  int run = 0;
  for (int c = 0; c < T_TOK; c += 64) {
    const int t = c + lane;
    const int i0 = topk_i[2 * t], i1 = topk_i[2 * t + 1];
    const bool hit = (i0 == e) || (i1 == e);
    unsigned long long m = __ballot(hit);
    int pre = __popcll(m & ((1ull << lane) - 1ull));
    if (hit) {
      int r = offv + run + pre;
      rows[r] = t;
      dest[2 * t + (i0 == e ? 0 : 1)] = r;
    }
    run += __popcll(m);
  }
}

// Swizzle (rule 21): LDS(row, chunk) = global(row, chunk ^ ((row>>1)&3)), chunk = 16B unit.
// gll16 dest linear; GLOBAL source chunk pre-XORed; ds_read applies the same XOR.

// ---- GEMM1: h = gelu(gather(x) @ w1T^T + b1), bf16 out ----
__global__ __launch_bounds__(256, 3) void gemm1_kernel(
    const unsigned short* __restrict__ xb, const unsigned short* __restrict__ w1T,
    const float* __restrict__ b1, const int* __restrict__ counts,
    const int* __restrict__ offsets, const int* __restrict__ rows,
    unsigned short* __restrict__ h) {
  const int hw = blockIdx.x;
  const int lid = (hw & 7) * (8192 >> 3) + (hw >> 3);
  const int nt = lid & 31;
  const int mt = (lid >> 5) & 31;
  const int e = lid >> 10;

  const int cnt = counts[e];
  if (mt * 128 >= cnt) return;
  const int off = offsets[e];
  const int t = threadIdx.x;
  const int lane = t & 63, wave = t >> 6;
  const int wm = wave >> 1, wn = wave & 1;

  __shared__ __align__(16) unsigned short lds[24576];  // 48KB: 3xA(4096) + 3xB(4096)
  unsigned short* ldsA = lds;
  unsigned short* ldsB = lds + 12288;

  const int tr = t >> 2;
  const int tcs = (t & 3) ^ ((t >> 3) & 3);  // swizzled source chunk
  const int a0 = mt * 128 + tr;
  const int g0 = rows[off + min(a0, cnt - 1)];
  const int g1 = rows[off + min(a0 + 64, cnt - 1)];
  const unsigned short* aptr0 = xb + (size_t)g0 * D_DIM + tcs * 8;
  const unsigned short* aptr1 = xb + (size_t)g1 * D_DIM + tcs * 8;
  const unsigned short* wb = w1T + (size_t)e * F_DIM * D_DIM;
  const unsigned short* bptr0 = wb + (size_t)(nt * 128 + tr) * D_DIM + tcs * 8;
  const unsigned short* bptr1 = bptr0 + (size_t)64 * D_DIM;

  const int col = lane & 15;
  float bias_v[4];
#pragma unroll
  for (int nf = 0; nf < 4; nf++)
    bias_v[nf] = b1[(size_t)e * F_DIM + nt * 128 + wn * 64 + nf * 16 + col];

  f32x4 acc[4][4];
  const f32x4 z = {0.f, 0.f, 0.f, 0.f};
#pragma unroll
  for (int i = 0; i < 4; i++)
#pragma unroll
    for (int j = 0; j < 4; j++) acc[i][j] = z;

  auto stage = [&](int buf, int kt) {
    const int kb = kt * 32;
    gll16(aptr0 + kb, ldsA + buf * 4096 + wave * 512);
    gll16(aptr1 + kb, ldsA + buf * 4096 + 2048 + wave * 512);
    gll16(bptr0 + kb, ldsB + buf * 4096 + wave * 512);
    gll16(bptr1 + kb, ldsB + buf * 4096 + 2048 + wave * 512);
  };

  asm volatile("s_waitcnt vmcnt(0)" ::: "memory");  // clean slate for counting
  stage(0, 0);
  stage(1, 1);

  const int rA = wm * 64 + (lane & 15);
  const int rB = wn * 64 + (lane & 15);
  const int ko = (((lane >> 4) ^ ((lane >> 1) & 3)) * 8);  // swizzled read chunk
  const int NK = D_DIM / 32;  // 32

  int cur = 0, nxt = 2;
  for (int kt = 0; kt < NK; ++kt) {
    if (kt + 2 < NK) {
      stage(nxt, kt + 2);
      asm volatile("s_waitcnt vmcnt(8)" ::: "memory");
    } else if (kt + 2 == NK) {
      asm volatile("s_waitcnt vmcnt(4)" ::: "memory");
    } else {
      asm volatile("s_waitcnt vmcnt(0)" ::: "memory");
    }
    __builtin_amdgcn_s_barrier();
    bf16x8 af[4], bfr[4];
#pragma unroll
    for (int mf = 0; mf < 4; mf++)
      af[mf] = *(const bf16x8*)&ldsA[cur * 4096 + (rA + mf * 16) * 32 + ko];
#pragma unroll
    for (int nf = 0; nf < 4; nf++)
      bfr[nf] = *(const bf16x8*)&ldsB[cur * 4096 + (rB + nf * 16) * 32 + ko];
#pragma unroll
    for (int mf = 0; mf < 4; mf++)
#pragma unroll
      for (int nf = 0; nf < 4; nf++)
        acc[mf][nf] = __builtin_amdgcn_mfma_f32_16x16x32_bf16(af[mf], bfr[nf], acc[mf][nf], 0, 0, 0);
    __builtin_amdgcn_s_barrier();
    cur = (cur == 2) ? 0 : cur + 1;
    nxt = (nxt == 2) ? 0 : nxt + 1;
  }

  // Full fence before reusing the pipeline LDS for the epilogue: raw s_barrier is
  // IntrNoMem (no compiler memory fence) — epilogue ds_writes could hoist into the
  // final K-iteration and race other waves' ds_reads. __syncthreads() fences both
  // compiler and HW (lgkmcnt drain + barrier).
  __syncthreads();

  // ---- LDS-staged epilogue: gelu+bias -> lds[128][136] -> 256B-coalesced stores ----
  const int valid = cnt - mt * 128;
  const int rq = (lane >> 4) * 4;
#pragma unroll
  for (int nf = 0; nf < 4; nf++) {
    const float bias = bias_v[nf];
#pragma unroll
    for (int mf = 0; mf < 4; mf++) {
#pragma unroll
      for (int r4 = 0; r4 < 4; r4++) {
        int r = wm * 64 + mf * 16 + rq + r4;
        int c = wn * 64 + nf * 16 + col;
        float v = acc[mf][nf][r4] + bias;
        v = 0.5f * v * (1.0f + erff(v * 0.7071067811865475f));
        lds[r * 136 + c] = f2bf(v);
      }
    }
  }
  __syncthreads();
  const int srow = t >> 4;         // 0..15
  const int scol = (t & 15) * 8;   // 0..120
#pragma unroll
  for (int i = 0; i < 8; i++) {
    int r = srow + i * 16;
    if (r < valid) {
      u16x8 v = *(const u16x8*)&lds[r * 136 + scol];
      *(u16x8*)&h[(size_t)(off + mt * 128 + r) * F_DIM + nt * 128 + scol] = v;
    }
  }
}

// ---- GEMM2: y = h @ w2T^T + b2, fp32 out ----
__global__ __launch_bounds__(256, 3) void gemm2_kernel(
    const unsigned short* __restrict__ h, const unsigned short* __restrict__ w2T,
    const float* __restrict__ b2, const int* __restrict__ counts,
    const int* __restrict__ offsets, float* __restrict__ y) {
  const int hw = blockIdx.x;
  const int lid = (hw & 7) * (2048 >> 3) + (hw >> 3);
  const int nt = lid & 7;
  const int mt = (lid >> 3) & 31;
  const int e = lid >> 8;

  const int cnt = counts[e];
  if (mt * 128 >= cnt) return;
  const int off = offsets[e];
  const int t = threadIdx.x;
  const int lane = t & 63, wave = t >> 6;
  const int wm = wave >> 1, wn = wave & 1;

  __shared__ __align__(16) unsigned short ldsA[3][4096];
  __shared__ __align__(16) unsigned short ldsB[3][4096];

  const int tr = t >> 2;
  const int tcs = (t & 3) ^ ((t >> 3) & 3);  // swizzled source chunk
  const int l0 = min(mt * 128 + tr, cnt - 1);
  const int l1 = min(mt * 128 + 64 + tr, cnt - 1);
  const unsigned short* aptr0 = h + (size_t)(off + l0) * F_DIM + tcs * 8;
  const unsigned short* aptr1 = h + (size_t)(off + l1) * F_DIM + tcs * 8;
  const unsigned short* wb = w2T + (size_t)e * D_DIM * F_DIM;
  const unsigned short* bptr0 = wb + (size_t)(nt * 128 + tr) * F_DIM + tcs * 8;
  const unsigned short* bptr1 = bptr0 + (size_t)64 * F_DIM;

  const int col = lane & 15;
  float bias_v[4];
#pragma unroll
  for (int nf = 0; nf < 4; nf++)
    bias_v[nf] = b2[(size_t)e * D_DIM + nt * 128 + wn * 64 + nf * 16 + col];

  f32x4 acc[4][4];
  const f32x4 z = {0.f, 0.f, 0.f, 0.f};
#pragma unroll
  for (int i = 0; i < 4; i++)
#pragma unroll
    for (int j = 0; j < 4; j++) acc[i][j] = z;

  auto stage = [&](int buf, int kt) {
    const int kb = kt * 32;
    gll16(aptr0 + kb, &ldsA[buf][wave * 512]);
    gll16(aptr1 + kb, &ldsA[buf][2048 + wave * 512]);
    gll16(bptr0 + kb, &ldsB[buf][wave * 512]);
    gll16(bptr1 + kb, &ldsB[buf][2048 + wave * 512]);
  };

  asm volatile("s_waitcnt vmcnt(0)" ::: "memory");
  stage(0, 0);
  stage(1, 1);

  const int rA = wm * 64 + (lane & 15);
  const int rB = wn * 64 + (lane & 15);
  const int ko = (((lane >> 4) ^ ((lane >> 1) & 3)) * 8);  // swizzled read chunk
  const int NK = F_DIM / 32;  // 128

  int cur = 0, nxt = 2;
  for (int kt = 0; kt < NK; ++kt) {
    if (kt + 2 < NK) {
      stage(nxt, kt + 2);
      asm volatile("s_waitcnt vmcnt(8)" ::: "memory");
    } else if (kt + 2 == NK) {
      asm volatile("s_waitcnt vmcnt(4)" ::: "memory");
    } else {
      asm volatile("s_waitcnt vmcnt(0)" ::: "memory");
    }
    __builtin_amdgcn_s_barrier();
    bf16x8 af[4], bfr[4];
#pragma unroll
    for (int mf = 0; mf < 4; mf++)
      af[mf] = *(const bf16x8*)&ldsA[cur][(rA + mf * 16) * 32 + ko];
#pragma unroll
    for (int nf = 0; nf < 4; nf++)
      bfr[nf] = *(const bf16x8*)&ldsB[cur][(rB + nf * 16) * 32 + ko];
#pragma unroll
    for (int mf = 0; mf < 4; mf++)
#pragma unroll
      for (int nf = 0; nf < 4; nf++)
        acc[mf][nf] = __builtin_amdgcn_mfma_f32_16x16x32_bf16(af[mf], bfr[nf], acc[mf][nf], 0, 0, 0);
    __builtin_amdgcn_s_barrier();
    cur = (cur == 2) ? 0 : cur + 1;
    nxt = (nxt == 2) ? 0 : nxt + 1;
  }

  const int valid = cnt - mt * 128;
  const int rq = (lane >> 4) * 4;
#pragma unroll
  for (int nf = 0; nf < 4; nf++) {
    const int c = nt * 128 + wn * 64 + nf * 16 + col;
    const float bias = bias_v[nf];
#pragma unroll
    for (int mf = 0; mf < 4; mf++) {
#pragma unroll
      for (int r4 = 0; r4 < 4; r4++) {
        int rloc = wm * 64 + mf * 16 + rq + r4;
        if (rloc < valid)
          y[(size_t)(off + mt * 128 + rloc) * D_DIM + c] = acc[mf][nf][r4] + bias;
      }
    }
  }
}

// ---- combine: out[t] = w0*y[r0] + w1*y[r1] ----
__global__ void combine_kernel(const float* __restrict__ y, const int* __restrict__ dest,
                               const float* __restrict__ tw, float* __restrict__ out) {
  const int n4 = T_TOK * D_DIM / 4;
  for (int i = blockIdx.x * blockDim.x + threadIdx.x; i < n4; i += gridDim.x * blockDim.x) {
    int tok = i >> 8;  // D/4 = 256
    int c = i & 255;
    int r0 = dest[2 * tok], r1 = dest[2 * tok + 1];
    float w0 = tw[2 * tok], w1 = tw[2 * tok + 1];
    float4 a = reinterpret_cast<const float4*>(y + (size_t)r0 * D_DIM)[c];
    float4 b = reinterpret_cast<const float4*>(y + (size_t)r1 * D_DIM)[c];
    float4 o;
    o.x = w0 * a.x + w1 * b.x; o.y = w0 * a.y + w1 * b.y;
    o.z = w0 * a.z + w1 * b.z; o.w = w0 * a.w + w1 * b.w;
    reinterpret_cast<float4*>(out + (size_t)tok * D_DIM)[c] = o;
  }
}

extern "C" void kernel_launch(void* const* d_in, const int* in_sizes, int n_in,
                              void* d_out, int out_size, void* d_ws, size_t ws_size,
                              hipStream_t stream) {
  (void)in_sizes; (void)n_in; (void)out_size; (void)ws_size;
  const float* x = (const float*)d_in[0];
  const float* gw = (const float*)d_in[1];
  const float* w1 = (const float*)d_in[2];
  const float* b1 = (const float*)d_in[3];
  const float* w2 = (const float*)d_in[4];
  const float* b2 = (const float*)d_in[5];
  float* out = (float*)d_out;
  char* ws = (char*)d_ws;

  int* counts = (int*)(ws + WS_COUNTS);
  int* offsets = (int*)(ws + WS_OFFSETS);
  int* topk_i = (int*)(ws + WS_TOPKI);
  float* topk_w = (float*)(ws + WS_TOPKW);
  int* rows = (int*)(ws + WS_ROWS);
  int* dest = (int*)(ws + WS_DEST);
  unsigned short* xb = (unsigned short*)(ws + WS_XB);
  unsigned short* w1T = (unsigned short*)(ws + WS_W1T);
  unsigned short* w2T = (unsigned short*)(ws + WS_W2T);
  unsigned short* hbuf = (unsigned short*)(ws + WS_H);
  float* ybuf = (float*)(ws + WS_Y);

  hipMemsetAsync(ws, 0, 4096, stream);
  gate_kernel<<<T_TOK / 4, 256, 0, stream>>>(x, gw, xb, topk_i, topk_w, counts);
  compact_kernel<<<E_NUM, 64, 0, stream>>>(topk_i, counts, offsets, rows, dest);
  // w1T right before gemm1, w2T right before gemm2: keep them L3-hot.
  transpose_cast_kernel<<<dim3(F_DIM / 64, D_DIM / 64, E_NUM), 256, 0, stream>>>(w1, w1T, D_DIM, F_DIM);
  gemm1_kernel<<<8192, 256, 0, stream>>>(xb, w1T, b1, counts, offsets, rows, hbuf);
  transpose_cast_kernel<<<dim3(D_DIM / 64, F_DIM / 64, E_NUM), 256, 0, stream>>>(w2, w2T, F_DIM, D_DIM);
  gemm2_kernel<<<2048, 256, 0, stream>>>(hbuf, w2T, b2, counts, offsets, ybuf);
  combine_kernel<<<2048, 256, 0, stream>>>(ybuf, dest, topk_w, out);
}